// Round 4
// baseline (315.819 us; speedup 1.0000x reference)
//
#include <hip/hip_runtime.h>
#include <hip/hip_bf16.h>
#include <stdint.h>

typedef __bf16 bf16_t;
typedef __bf16 bf16x8 __attribute__((ext_vector_type(8)));
typedef float f32x16 __attribute__((ext_vector_type(16)));

#define TILE 128
#define BK 64   // 128x64 bf16 tile = 16 KB per matrix, 32 KB LDS total

// async 16B global -> LDS (global_load_lds_dwordx4).
__device__ __forceinline__ void async_copy16(const bf16_t* g, bf16_t* l) {
    __builtin_amdgcn_global_load_lds(
        (const __attribute__((address_space(1))) unsigned int*)(uintptr_t)g,
        (__attribute__((address_space(3))) unsigned int*)(uintptr_t)l,
        16, 0, 0);
}

// ---------------- core NT-GEMM tile (shared by both kernels) ----------------
// 128x128 tile, 256 thr = 4 waves (2x2), wave 64x64 via 2x2 MFMA 32x32x16.
// LDS XOR-swizzled 8-elem chunks: chunk (row,kc) at index row*8+(kc^(row&7)).
struct CoreOut { f32x16 acc[2][2]; };

__device__ __forceinline__ void gemm_core(
    const bf16_t* __restrict__ Ab, const bf16_t* __restrict__ Bb,
    int blockM, int blockN, int K,
    bf16_t* As, bf16_t* Bs, f32x16 (&acc)[2][2])
{
    const int t    = threadIdx.x;
    const int lane = t & 63;
    const int r32  = lane & 31;
    const int half = lane >> 5;
    const int kx   = r32 & 7;

    const bf16_t* gA[4]; const bf16_t* gB[4];
    bf16_t* lA[4]; bf16_t* lB[4];
    #pragma unroll
    for (int j = 0; j < 4; j++) {
        int c   = t + j * 256;
        int row = c >> 3;
        int kcl = (c & 7) ^ (row & 7);
        gA[j] = Ab + (long)(blockM + row) * K + kcl * 8;
        gB[j] = Bb + (long)(blockN + row) * K + kcl * 8;
        lA[j] = &As[c * 8];
        lB[j] = &Bs[c * 8];
    }
    const int wave = t >> 6;
    const int wm   = (wave >> 1) * 64;
    const int wn   = (wave & 1) * 64;

    for (int k0 = 0; k0 < K; k0 += BK) {
        #pragma unroll
        for (int j = 0; j < 4; j++) async_copy16(gA[j] + k0, lA[j]);
        #pragma unroll
        for (int j = 0; j < 4; j++) async_copy16(gB[j] + k0, lB[j]);
        __syncthreads();

        #pragma unroll
        for (int ks = 0; ks < 4; ks++) {
            const int kc = ks * 2 + half;
            bf16x8 af[2], bfr[2];
            #pragma unroll
            for (int i = 0; i < 2; i++) {
                int R = wm + i * 32 + r32;
                af[i] = *(const bf16x8*)&As[(R * 8 + (kc ^ kx)) * 8];
            }
            #pragma unroll
            for (int j = 0; j < 2; j++) {
                int C = wn + j * 32 + r32;
                bfr[j] = *(const bf16x8*)&Bs[(C * 8 + (kc ^ kx)) * 8];
            }
            #pragma unroll
            for (int i = 0; i < 2; i++)
                #pragma unroll
                for (int j = 0; j < 2; j++)
                    acc[i][j] = __builtin_amdgcn_mfma_f32_32x32x16_bf16(
                                    af[i], bfr[j], acc[i][j], 0, 0, 0);
        }
        __syncthreads();
    }
}

// supertile swizzle: sweep all mbT rows for strips of SW n-cols (L2 locality)
__device__ __forceinline__ void swizzle_tiles(int bid, int mbT, int /*nbT*/,
                                              int& bm, int& bn)
{
    const int SW = 4;
    int strip = bid / (mbT * SW);
    int rem   = bid - strip * (mbT * SW);
    bm = rem / SW;
    bn = strip * SW + (rem - bm * SW);
}

// ------------- steps 4/5 kernel: Sc = relu(Qp Kp^T), out = Sc VpT^T ---------
template<bool OUT_F32, bool RELU>
__global__ __launch_bounds__(256, 2)
void gemm_bt(const bf16_t* __restrict__ A, const bf16_t* __restrict__ B,
             void* __restrict__ Cp, int K, int ldc,
             long sAb, long sBb, long sCb)
{
    __shared__ bf16_t As[TILE * BK];
    __shared__ bf16_t Bs[TILE * BK];

    const int b  = blockIdx.z;
    int bm, bn;
    swizzle_tiles(blockIdx.y * gridDim.x + blockIdx.x, gridDim.y, gridDim.x, bm, bn);
    const int blockM = bm * TILE, blockN = bn * TILE;

    f32x16 acc[2][2] = {};
    gemm_core(A + sAb * (long)b, B + sBb * (long)b, blockM, blockN, K, As, Bs, acc);

    const int lane = threadIdx.x & 63;
    const int wave = threadIdx.x >> 6;
    const int wm   = (wave >> 1) * 64;
    const int wn   = (wave & 1) * 64;
    const int r32  = lane & 31;
    const int half = lane >> 5;

    float*  Cf = (float*) Cp + sCb * (long)b;
    bf16_t* Ch = (bf16_t*)Cp + sCb * (long)b;
    #pragma unroll
    for (int ti = 0; ti < 2; ti++)
        #pragma unroll
        for (int tj = 0; tj < 2; tj++) {
            const int gcol = blockN + wn + tj * 32 + r32;
            #pragma unroll
            for (int reg = 0; reg < 16; reg++) {
                const int grow = blockM + wm + ti * 32
                               + (reg & 3) + 8 * (reg >> 2) + 4 * half;
                float vv = acc[ti][tj][reg];
                if (RELU) vv = fmaxf(vv, 0.f);
                if (OUT_F32) Cf[(long)grow * ldc + gcol] = vv;
                else         Ch[(long)grow * ldc + gcol] = (bf16_t)vv;
            }
        }
}

// ------------- merged projection kernel: Qp, Kp, VpT in ONE dispatch --------
// flat grid 1536: [0,512) Qp (64x8 tiles), [512,1024) Kp, [1024,1536) VpT
// (4 batches x 8x16 tiles). All K=1024, bf16 out.
__global__ __launch_bounds__(256, 2)
void gemm_proj(const bf16_t* __restrict__ qb, const bf16_t* __restrict__ kb,
               const bf16_t* __restrict__ vb, const bf16_t* __restrict__ Wqb,
               const bf16_t* __restrict__ Wkb, const bf16_t* __restrict__ Wvb,
               const float* __restrict__ bq, const float* __restrict__ bk,
               const float* __restrict__ bv,
               bf16_t* __restrict__ Qp, bf16_t* __restrict__ Kp,
               bf16_t* __restrict__ VpT)
{
    __shared__ bf16_t As[TILE * BK];
    __shared__ bf16_t Bs[TILE * BK];

    const int S = 2048, D = 1024;
    const int bid = blockIdx.x;

    const bf16_t *A, *B;
    const float* bias;
    bf16_t* C;
    int ldc, mbT, local, biasMode;
    if (bid < 1024) {          // Q or K projection: A[8192,1024] x W[1024,1024]
        int sec = bid >> 9;    // 0=Q, 1=K
        local = bid & 511;
        A = sec ? kb : qb;  B = sec ? Wkb : Wqb;
        bias = sec ? bk : bq;  C = sec ? Kp : Qp;
        ldc = D; mbT = 64; biasMode = 1;
    } else {                   // VpT: A=Wv[1024,1024], B=v_b[2048,1024], row bias
        int l2 = bid - 1024;
        int z  = l2 >> 7;      // batch
        local  = l2 & 127;
        A = Wvb;  B = vb + (long)z * S * D;
        bias = bv;  C = VpT + (long)z * D * S;
        ldc = S; mbT = 8; biasMode = 2;
    }
    int bm, bn;
    swizzle_tiles(local, mbT, 0, bm, bn);
    const int blockM = bm * TILE, blockN = bn * TILE;

    f32x16 acc[2][2] = {};
    gemm_core(A, B, blockM, blockN, 1024, As, Bs, acc);

    const int lane = threadIdx.x & 63;
    const int wave = threadIdx.x >> 6;
    const int wm   = (wave >> 1) * 64;
    const int wn   = (wave & 1) * 64;
    const int r32  = lane & 31;
    const int half = lane >> 5;

    #pragma unroll
    for (int ti = 0; ti < 2; ti++)
        #pragma unroll
        for (int tj = 0; tj < 2; tj++) {
            const int gcol = blockN + wn + tj * 32 + r32;
            const float bc = (biasMode == 1) ? bias[gcol] : 0.f;
            #pragma unroll
            for (int reg = 0; reg < 16; reg++) {
                const int grow = blockM + wm + ti * 32
                               + (reg & 3) + 8 * (reg >> 2) + 4 * half;
                float vv = acc[ti][tj][reg] + ((biasMode == 2) ? bias[grow] : bc);
                C[(long)grow * ldc + gcol] = (bf16_t)vv;
            }
        }
}

// ---------------- fp32 -> bf16 cast of q,k,v,Wq,Wk,Wv ----------------------
__global__ __launch_bounds__(256)
void cast_all_kernel(const float* __restrict__ q, const float* __restrict__ k,
                     const float* __restrict__ v, const float* __restrict__ Wq,
                     const float* __restrict__ Wk, const float* __restrict__ Wv,
                     bf16_t* __restrict__ ws)
{
    const long BIG = 1048576;   // 8192*1024 / 8
    const long SMALL = 131072;  // 1024*1024 / 8
    long id = (long)blockIdx.x * blockDim.x + threadIdx.x;
    const float* src; bf16_t* dst;
    if (id < 3 * BIG) {
        int s = (int)(id / BIG);
        long off = (id - (long)s * BIG) * 8;
        src = (s == 0 ? q : s == 1 ? k : v) + off;
        dst = ws + (long)s * 8388608 + off;
    } else {
        long id2 = id - 3 * BIG;
        int s = (int)(id2 / SMALL);
        long off = (id2 - (long)s * SMALL) * 8;
        src = (s == 0 ? Wq : s == 1 ? Wk : Wv) + off;
        dst = ws + 25165824L + (long)s * 1048576 + off;
    }
    float4 v0 = ((const float4*)src)[0];
    float4 v1 = ((const float4*)src)[1];
    alignas(16) bf16_t o[8];
    o[0]=(bf16_t)v0.x; o[1]=(bf16_t)v0.y; o[2]=(bf16_t)v0.z; o[3]=(bf16_t)v0.w;
    o[4]=(bf16_t)v1.x; o[5]=(bf16_t)v1.y; o[6]=(bf16_t)v1.z; o[7]=(bf16_t)v1.w;
    *(uint4*)dst = *(const uint4*)o;
}

extern "C" void kernel_launch(void* const* d_in, const int* in_sizes, int n_in,
                              void* d_out, int out_size, void* d_ws, size_t ws_size,
                              hipStream_t stream)
{
    const float* q   = (const float*)d_in[0];
    const float* k   = (const float*)d_in[1];
    const float* v   = (const float*)d_in[2];
    const float* Wq  = (const float*)d_in[3];
    const float* bq  = (const float*)d_in[4];
    const float* Wk  = (const float*)d_in[5];
    const float* bk  = (const float*)d_in[6];
    const float* Wv  = (const float*)d_in[7];
    const float* bv  = (const float*)d_in[8];

    const int B = 4, S = 2048, D = 1024;

    // workspace (bf16 element offsets):
    //   qb 0, kb 8388608, vb 16777216 (dead after proj; Sc aliases qb+kb)
    //   Wqb 25165824, Wkb 26214400, Wvb 27262976
    //   Qp 28311552, Kp 36700160, VpT 45088768   (total ~107 MB)
    bf16_t* ws  = (bf16_t*)d_ws;
    bf16_t* qb  = ws;
    bf16_t* kb  = ws + 8388608L;
    bf16_t* vb  = ws + 16777216L;
    bf16_t* Wqb = ws + 25165824L;
    bf16_t* Wkb = ws + 26214400L;
    bf16_t* Wvb = ws + 27262976L;
    bf16_t* Qp  = ws + 28311552L;
    bf16_t* Kp  = ws + 36700160L;
    bf16_t* VpT = ws + 45088768L;
    bf16_t* Sc  = ws;              // aliases qb+kb (dead by step 3)

    dim3 blk(256);

    // 1) cast everything to bf16
    cast_all_kernel<<<dim3(13824), blk, 0, stream>>>(q, k, v, Wq, Wk, Wv, ws);

    // 2) merged projections: Qp, Kp, VpT in one 1536-block dispatch
    gemm_proj<<<dim3(1536), blk, 0, stream>>>(
        qb, kb, vb, Wqb, Wkb, Wvb, bq, bk, bv, Qp, Kp, VpT);

    // 3) Sc[b] = relu(Qp_b @ Kp_b^T)  [2048 x 2048, K=1024], bf16 out
    gemm_bt<false, true><<<dim3(S / TILE, S / TILE, B), blk, 0, stream>>>(
        Qp, Kp, Sc, D, S, (long)S * D, (long)S * D, (long)S * S);

    // 4) out[b] = Sc_b @ VpT_b^T  [2048 x 1024, K=2048], fp32 out
    gemm_bt<true, false><<<dim3(D / TILE, S / TILE, B), blk, 0, stream>>>(
        Sc, VpT, d_out, S, D, (long)S * S, (long)D * S, (long)S * D);
}

// Round 5
// 308.551 us; speedup vs baseline: 1.0236x; 1.0236x over previous
//
#include <hip/hip_runtime.h>
#include <hip/hip_bf16.h>
#include <stdint.h>

typedef __bf16 bf16_t;
typedef __bf16 bf16x8 __attribute__((ext_vector_type(8)));
typedef float f32x16 __attribute__((ext_vector_type(16)));

#define TILE 128
#define BK 64   // 128x64 bf16 tile = 16 KB per matrix, 32 KB LDS total

// async 16B global -> LDS (global_load_lds_dwordx4).
// LDS dest must be wave-uniform base + lane*16 -- chunk layout guarantees it.
__device__ __forceinline__ void async_copy16(const bf16_t* g, bf16_t* l) {
    __builtin_amdgcn_global_load_lds(
        (const __attribute__((address_space(1))) unsigned int*)(uintptr_t)g,
        (__attribute__((address_space(3))) unsigned int*)(uintptr_t)l,
        16, 0, 0);
}

// NT GEMM, all-bf16: C[m,n] = op( sum_k A[m,k]*B[n,k] + bias )
// 128x128 tile, 256 thr = 4 waves (2x2), each wave 64x64 via 2x2 MFMA 32x32x16.
// LDS: 8-element chunks, XOR-swizzled: chunk (row,kc) stored at index row*8+(kc^(row&7)).
// __launch_bounds__(256,4): 4 waves/EU -> 4 blocks/CU (LDS 32KB*4=128KB<=160KB,
// VGPR 64*4<=512). At 2 blocks/CU the barrier drain was unmasked (R4: MfmaUtil 27%).
// BIAS_MODE: 0=none, 1=bias[col], 2=bias[row]
template<bool OUT_F32, bool RELU, int BIAS_MODE>
__global__ __launch_bounds__(256, 4)
void gemm_bt(const bf16_t* __restrict__ A, const bf16_t* __restrict__ B,
             const float* __restrict__ bias, void* __restrict__ Cp,
             int K, int ldc, long sAb, long sBb, long sCb)
{
    __shared__ bf16_t As[TILE * BK];
    __shared__ bf16_t Bs[TILE * BK];

    const int b  = blockIdx.z;
    // supertile swizzle: sweep all M for a strip of SW n-columns (L2 locality)
    const int nb = gridDim.x, mb = gridDim.y;
    const int SW = 4;
    int bid   = blockIdx.y * nb + blockIdx.x;
    int strip = bid / (mb * SW);
    int rem   = bid - strip * (mb * SW);
    int bm    = rem / SW;
    int bn    = strip * SW + (rem - bm * SW);
    const int blockM = bm * TILE;
    const int blockN = bn * TILE;

    const int t    = threadIdx.x;
    const int lane = t & 63;
    const int wave = t >> 6;
    const int wm   = (wave >> 1) * 64;
    const int wn   = (wave & 1) * 64;
    const int r32  = lane & 31;       // row within 32x32 tile (A) / col (B)
    const int half = lane >> 5;       // k-half selector
    const int kx   = r32 & 7;         // xor key for swizzled frag reads

    f32x16 acc[2][2] = {};

    const bf16_t* Ab = A + sAb * (long)b;
    const bf16_t* Bb = B + sBb * (long)b;

    // staging: stored chunk c = t + j*256; row=c>>3, stored kc=c&7,
    // logical kc = stored ^ (row&7). 4 chunks each for A and B per K-step.
    const bf16_t* gA[4]; const bf16_t* gB[4];
    bf16_t* lA[4]; bf16_t* lB[4];
    #pragma unroll
    for (int j = 0; j < 4; j++) {
        int c   = t + j * 256;
        int row = c >> 3;
        int kcl = (c & 7) ^ (row & 7);
        gA[j] = Ab + (long)(blockM + row) * K + kcl * 8;
        gB[j] = Bb + (long)(blockN + row) * K + kcl * 8;
        lA[j] = &As[c * 8];
        lB[j] = &Bs[c * 8];
    }

    for (int k0 = 0; k0 < K; k0 += BK) {
        #pragma unroll
        for (int j = 0; j < 4; j++) async_copy16(gA[j] + k0, lA[j]);
        #pragma unroll
        for (int j = 0; j < 4; j++) async_copy16(gB[j] + k0, lB[j]);
        __syncthreads();

        #pragma unroll
        for (int ks = 0; ks < 4; ks++) {
            const int kc = ks * 2 + half;       // logical 8-elem chunk in BK
            bf16x8 af[2], bfr[2];
            #pragma unroll
            for (int i = 0; i < 2; i++) {
                int R = wm + i * 32 + r32;
                af[i] = *(const bf16x8*)&As[(R * 8 + (kc ^ kx)) * 8];
            }
            #pragma unroll
            for (int j = 0; j < 2; j++) {
                int C = wn + j * 32 + r32;
                bfr[j] = *(const bf16x8*)&Bs[(C * 8 + (kc ^ kx)) * 8];
            }
            #pragma unroll
            for (int i = 0; i < 2; i++)
                #pragma unroll
                for (int j = 0; j < 2; j++)
                    acc[i][j] = __builtin_amdgcn_mfma_f32_32x32x16_bf16(
                                    af[i], bfr[j], acc[i][j], 0, 0, 0);
        }
        __syncthreads();
    }

    // epilogue: C/D layout col=lane&31, row=(reg&3)+8*(reg>>2)+4*half
    float*  Cf = (float*) Cp + sCb * (long)b;
    bf16_t* Ch = (bf16_t*)Cp + sCb * (long)b;
    #pragma unroll
    for (int ti = 0; ti < 2; ti++) {
        #pragma unroll
        for (int tj = 0; tj < 2; tj++) {
            const int gcol = blockN + wn + tj * 32 + r32;
            float bc = 0.f;
            if (BIAS_MODE == 1) bc = bias[gcol];
            #pragma unroll
            for (int reg = 0; reg < 16; reg++) {
                const int grow = blockM + wm + ti * 32
                               + (reg & 3) + 8 * (reg >> 2) + 4 * half;
                float vv = acc[ti][tj][reg];
                if (BIAS_MODE == 1) vv += bc;
                if (BIAS_MODE == 2) vv += bias[grow];
                if (RELU) vv = fmaxf(vv, 0.f);
                if (OUT_F32) Cf[(long)grow * ldc + gcol] = vv;
                else         Ch[(long)grow * ldc + gcol] = (bf16_t)vv;
            }
        }
    }
}

// One-shot fp32 -> bf16 cast of q,k,v,Wq,Wk,Wv into workspace.
__global__ __launch_bounds__(256)
void cast_all_kernel(const float* __restrict__ q, const float* __restrict__ k,
                     const float* __restrict__ v, const float* __restrict__ Wq,
                     const float* __restrict__ Wk, const float* __restrict__ Wv,
                     bf16_t* __restrict__ ws)
{
    const long BIG = 1048576;   // 8192*1024 / 8
    const long SMALL = 131072;  // 1024*1024 / 8
    long id = (long)blockIdx.x * blockDim.x + threadIdx.x;
    const float* src; bf16_t* dst;
    if (id < 3 * BIG) {
        int s = (int)(id / BIG);
        long off = (id - (long)s * BIG) * 8;
        src = (s == 0 ? q : s == 1 ? k : v) + off;
        dst = ws + (long)s * 8388608 + off;
    } else {
        long id2 = id - 3 * BIG;
        int s = (int)(id2 / SMALL);
        long off = (id2 - (long)s * SMALL) * 8;
        src = (s == 0 ? Wq : s == 1 ? Wk : Wv) + off;
        dst = ws + 25165824L + (long)s * 1048576 + off;
    }
    float4 v0 = ((const float4*)src)[0];
    float4 v1 = ((const float4*)src)[1];
    alignas(16) bf16_t o[8];
    o[0]=(bf16_t)v0.x; o[1]=(bf16_t)v0.y; o[2]=(bf16_t)v0.z; o[3]=(bf16_t)v0.w;
    o[4]=(bf16_t)v1.x; o[5]=(bf16_t)v1.y; o[6]=(bf16_t)v1.z; o[7]=(bf16_t)v1.w;
    *(uint4*)dst = *(const uint4*)o;
}

extern "C" void kernel_launch(void* const* d_in, const int* in_sizes, int n_in,
                              void* d_out, int out_size, void* d_ws, size_t ws_size,
                              hipStream_t stream)
{
    const float* q   = (const float*)d_in[0];
    const float* k   = (const float*)d_in[1];
    const float* v   = (const float*)d_in[2];
    const float* Wq  = (const float*)d_in[3];
    const float* bq  = (const float*)d_in[4];
    const float* Wk  = (const float*)d_in[5];
    const float* bk  = (const float*)d_in[6];
    const float* Wv  = (const float*)d_in[7];
    const float* bv  = (const float*)d_in[8];

    const int B = 4, S = 2048, D = 1024;
    const int BS = B * S; // 8192

    // workspace (bf16 element offsets):
    //   qb 0, kb 8388608, vb 16777216 (dead after their GEMM; Sc aliases qb+kb)
    //   Wqb 25165824, Wkb 26214400, Wvb 27262976
    //   Qp 28311552, Kp 36700160, VpT 45088768   (total ~107 MB)
    bf16_t* ws  = (bf16_t*)d_ws;
    bf16_t* qb  = ws;
    bf16_t* kb  = ws + 8388608L;
    bf16_t* vb  = ws + 16777216L;
    bf16_t* Wqb = ws + 25165824L;
    bf16_t* Wkb = ws + 26214400L;
    bf16_t* Wvb = ws + 27262976L;
    bf16_t* Qp  = ws + 28311552L;
    bf16_t* Kp  = ws + 36700160L;
    bf16_t* VpT = ws + 45088768L;
    bf16_t* Sc  = ws;              // aliases qb+kb (both dead by step 4)

    dim3 blk(256);

    cast_all_kernel<<<dim3(13824), blk, 0, stream>>>(q, k, v, Wq, Wk, Wv, ws);

    // Qp = qb @ Wqb^T + bq   [M=8192, N=1024, K=1024]
    gemm_bt<false, false, 1><<<dim3(D / TILE, BS / TILE, 1), blk, 0, stream>>>(
        qb, Wqb, bq, Qp, D, D, 0L, 0L, 0L);

    // Kp = kb @ Wkb^T + bk
    gemm_bt<false, false, 1><<<dim3(D / TILE, BS / TILE, 1), blk, 0, stream>>>(
        kb, Wkb, bk, Kp, D, D, 0L, 0L, 0L);

    // VpT[b] = (v_b @ Wv^T + bv)^T : A=Wvb [1024,1024], B=vb_b [2048,1024], row bias
    gemm_bt<false, false, 2><<<dim3(S / TILE, D / TILE, B), blk, 0, stream>>>(
        Wvb, vb, bv, VpT, D, S, 0L, (long)S * D, (long)D * S);

    // Sc[b] = relu(Qp_b @ Kp_b^T)  [2048 x 2048, K=1024], bf16 out
    gemm_bt<false, true, 0><<<dim3(S / TILE, S / TILE, B), blk, 0, stream>>>(
        Qp, Kp, nullptr, Sc, D, S, (long)S * D, (long)S * D, (long)S * S);

    // out[b] = Sc_b @ VpT_b^T  [2048 x 1024, K=2048], fp32 out
    gemm_bt<true, false, 0><<<dim3(D / TILE, S / TILE, B), blk, 0, stream>>>(
        Sc, VpT, nullptr, d_out, S, D, (long)S * S, (long)D * S, (long)S * D);
}